// Round 8
// baseline (262.839 us; speedup 1.0000x reference)
//
#include <hip/hip_runtime.h>
#include <hip/hip_fp16.h>

// GCN layer, N=8192, E=262144, D=256 — SINGLE persistent kernel.
// out = adj_norm @ (X @ W^T) + b  (adj_norm rows sum to 1 -> bias commutes)
// Phases: A) zero deg + W->(Wh,Wl) fp16 split + barrier init
//         B) CSR scatter (no dedup; duplicates ~512/262144, handled at read)
//         C) Y(fp16) = X @ (Wh+Wl)^T  via fp16 MFMA 2-pass (round-7-identical)
//         D) per-node: LDS dedup + gather + /(ndist+1) + bias
// Grid sync: device-scope atomic barriers; 512 blocks = 2/CU co-resident
// (launch_bounds(256,2), VGPR<=256, LDS ~2.5KB -> guaranteed).

#define NNODES 8192
#define DFEAT  256
#define MAXDEG 192          // Poisson(32): P(deg>=192) ~ 1e-80
#define NBLK   512
#define NTHR   256
#define MAGIC  0x13572468u  // != 0xAAAAAAAA poison

typedef __attribute__((ext_vector_type(8))) _Float16 f16x8;
typedef __attribute__((ext_vector_type(4))) _Float16 f16x4;
typedef __attribute__((ext_vector_type(4))) float    f32x4;

__device__ inline void grid_barrier(unsigned* ctr) {
  __syncthreads();
  if (threadIdx.x == 0) {
    __threadfence();                                   // release (L2 writeback)
    atomicAdd(ctr, 1u);
    while (atomicAdd(ctr, 0u) < NBLK) __builtin_amdgcn_s_sleep(8);
    __threadfence();                                   // acquire (invalidate stale)
  }
  __syncthreads();
}

__global__ __launch_bounds__(NTHR, 2) void gcn_all(
    const float* __restrict__ X, const int* __restrict__ ei,
    const float* __restrict__ W, const float* __restrict__ bias, int E,
    unsigned* __restrict__ ctl, int* __restrict__ deg,
    unsigned short* __restrict__ adj, _Float16* __restrict__ Wh,
    _Float16* __restrict__ Wl, _Float16* __restrict__ Y,
    float* __restrict__ out)
{
  const int bid  = blockIdx.x, tid = threadIdx.x;
  const int gtid = bid * NTHR + tid;
  const int wave = tid >> 6, lane = tid & 63;

  // ---------------- phase A: zero deg, W split-convert, barrier init -------
  if (gtid < NNODES) deg[gtid] = 0;
  if (gtid < DFEAT * DFEAT / 4) {
    float4 v = *(const float4*)(W + (size_t)gtid * 4);
    f16x4 h = {(_Float16)v.x, (_Float16)v.y, (_Float16)v.z, (_Float16)v.w};
    f16x4 l = {(_Float16)(v.x - (float)h[0]), (_Float16)(v.y - (float)h[1]),
               (_Float16)(v.z - (float)h[2]), (_Float16)(v.w - (float)h[3])};
    *(f16x4*)(Wh + (size_t)gtid * 4) = h;
    *(f16x4*)(Wl + (size_t)gtid * 4) = l;
  }
  if (bid == 0) {                      // zero counters, then open the gate
    __syncthreads();
    if (tid >= 1 && tid <= 3) ctl[tid * 32] = 0;      // c1,c2,c3 (128B apart)
    __syncthreads();
    if (tid == 0) { __threadfence(); atomicExch(&ctl[0], MAGIC); }
  }
  if (tid == 0)
    while (atomicAdd(&ctl[0], 0u) != MAGIC) __builtin_amdgcn_s_sleep(8);
  __syncthreads();
  grid_barrier(&ctl[32]);

  // ---------------- phase B: CSR scatter (append, dedup deferred) ----------
  for (int e = gtid; e < E; e += NBLK * NTHR) {
    int s = ei[e];                     // edge_index[0][e]
    int d = ei[E + e];                 // edge_index[1][e]
    int pos = atomicAdd(&deg[s], 1);
    if (pos < MAXDEG) adj[(size_t)s * MAXDEG + pos] = (unsigned short)d;
  }
  grid_barrier(&ctl[64]);

  // ---------------- phase C: Y = X @ (Wh+Wl)^T, fp16 MFMA (round-7 body) ---
  {
    const int row0 = (bid >> 2) * 64 + wave * 16;     // 128 row-tiles
    const int col0 = (bid & 3) * 64;                  // 4 col-tiles
    const int lr = lane & 15;
    const int kh = (lane >> 4) * 8;

    f32x4 acc[4];
#pragma unroll
    for (int i = 0; i < 4; ++i) acc[i] = (f32x4){0.f, 0.f, 0.f, 0.f};

    const float*    ap  = X  + (size_t)(row0 + lr) * DFEAT + kh;
    const _Float16* bhp = Wh + (size_t)(col0 + lr) * DFEAT + kh;
    const _Float16* blp = Wl + (size_t)(col0 + lr) * DFEAT + kh;

#pragma unroll
    for (int k0 = 0; k0 < DFEAT; k0 += 32) {
      float4 x0 = *(const float4*)(ap + k0);
      float4 x1 = *(const float4*)(ap + k0 + 4);
      f16x8 a = {(_Float16)x0.x, (_Float16)x0.y, (_Float16)x0.z, (_Float16)x0.w,
                 (_Float16)x1.x, (_Float16)x1.y, (_Float16)x1.z, (_Float16)x1.w};
#pragma unroll
      for (int nt = 0; nt < 4; ++nt) {
        f16x8 bh = *(const f16x8*)(bhp + k0 + nt * 16 * DFEAT);
        f16x8 bl = *(const f16x8*)(blp + k0 + nt * 16 * DFEAT);
        acc[nt] = __builtin_amdgcn_mfma_f32_16x16x32_f16(a, bh, acc[nt], 0, 0, 0);
        acc[nt] = __builtin_amdgcn_mfma_f32_16x16x32_f16(a, bl, acc[nt], 0, 0, 0);
      }
    }
    const int crow = row0 + (lane >> 4) * 4;          // C/D: col=lane&15, row=(lane>>4)*4+r
    const int ccol = col0 + lr;
#pragma unroll
    for (int nt = 0; nt < 4; ++nt)
#pragma unroll
      for (int r = 0; r < 4; ++r)
        Y[(size_t)(crow + r) * DFEAT + ccol + nt * 16] = (_Float16)acc[nt][r];
  }
  grid_barrier(&ctl[96]);

  // ---------------- phase D: dedup + gather + normalize + bias -------------
  // One wave per node (4 nodes in flight per block); lane = 4 channels (8B loads).
  // Self-edge: counted once in list + once as self term -> diagonal 2.0, matching
  // reference adj+I; divisor = ndistinct + 1.
  {
    __shared__ unsigned short listS[4][MAXDEG];
    __shared__ unsigned char  keepS[4][MAXDEG];
    unsigned short* list = listS[wave];
    unsigned char*  keep = keepS[wave];
    const int ch4 = lane * 4;
    const float4 b4 = *(const float4*)(bias + ch4);

    for (int node = bid * 4 + wave; node < NNODES; node += NBLK * 4) {
      int d = atomicAdd(&deg[node], 0);               // coherent read
      if (d > MAXDEG) d = MAXDEG;

      for (int base = 0; base < d; base += 64)
        if (base + lane < d)
          list[base + lane] = adj[(size_t)node * MAXDEG + base + lane];
      // same-wave LDS producer->consumer: lockstep + compiler lgkmcnt

      int ndist = 0;
#pragma unroll
      for (int base = 0; base < MAXDEG; base += 64) {
        int idx = base + lane;
        bool kp = false;
        if (idx < d) {
          unsigned short v = list[idx];
          kp = true;
          for (int k = 0; k < idx; ++k)
            if (list[k] == v) { kp = false; break; }
        }
        keep[idx] = kp ? 1 : 0;
        ndist += __popcll(__ballot(kp));
      }

      f16x4 sv = *(const f16x4*)(Y + (size_t)node * DFEAT + ch4);  // self (+I)
      float ax = (float)sv[0], ay = (float)sv[1], az = (float)sv[2], aw = (float)sv[3];

      int k = 0;
      for (; k + 4 <= d; k += 4) {
        int j0 = list[k], j1 = list[k + 1], j2 = list[k + 2], j3 = list[k + 3];
        float w0 = keep[k], w1 = keep[k + 1], w2 = keep[k + 2], w3 = keep[k + 3];
        f16x4 r0 = *(const f16x4*)(Y + (size_t)j0 * DFEAT + ch4);
        f16x4 r1 = *(const f16x4*)(Y + (size_t)j1 * DFEAT + ch4);
        f16x4 r2 = *(const f16x4*)(Y + (size_t)j2 * DFEAT + ch4);
        f16x4 r3 = *(const f16x4*)(Y + (size_t)j3 * DFEAT + ch4);
        ax += w0 * (float)r0[0] + w1 * (float)r1[0] + w2 * (float)r2[0] + w3 * (float)r3[0];
        ay += w0 * (float)r0[1] + w1 * (float)r1[1] + w2 * (float)r2[1] + w3 * (float)r3[1];
        az += w0 * (float)r0[2] + w1 * (float)r1[2] + w2 * (float)r2[2] + w3 * (float)r3[2];
        aw += w0 * (float)r0[3] + w1 * (float)r1[3] + w2 * (float)r2[3] + w3 * (float)r3[3];
      }
      for (; k < d; ++k) {
        float w0 = keep[k];
        f16x4 r0 = *(const f16x4*)(Y + (size_t)list[k] * DFEAT + ch4);
        ax += w0 * (float)r0[0]; ay += w0 * (float)r0[1];
        az += w0 * (float)r0[2]; aw += w0 * (float)r0[3];
      }

      float inv = 1.f / (float)(ndist + 1);
      float4 o = {ax * inv + b4.x, ay * inv + b4.y,
                  az * inv + b4.z, aw * inv + b4.w};
      *(float4*)(out + (size_t)node * DFEAT + ch4) = o;
    }
  }
}

extern "C" void kernel_launch(void* const* d_in, const int* in_sizes, int n_in,
                              void* d_out, int out_size, void* d_ws, size_t ws_size,
                              hipStream_t stream) {
  const float* x  = (const float*)d_in[0];
  const int*   ei = (const int*)d_in[1];
  const float* W  = (const float*)d_in[2];
  const float* b  = (const float*)d_in[3];
  float* out = (float*)d_out;
  const int E = in_sizes[1] / 2;

  // workspace layout (256B-aligned)
  char* p = (char*)d_ws;
  size_t off = 0;
  auto take = [&](size_t bytes) { char* r = p + off; off = (off + bytes + 255) & ~(size_t)255; return r; };
  unsigned*       ctl = (unsigned*)       take(512);                            // 4 counters, 128B apart
  int*            deg = (int*)            take((size_t)NNODES * 4);             // 32 KB
  unsigned short* adj = (unsigned short*) take((size_t)NNODES * MAXDEG * 2);    // 3 MB
  _Float16*       Wh  = (_Float16*)       take((size_t)DFEAT * DFEAT * 2);      // 128 KB
  _Float16*       Wl  = (_Float16*)       take((size_t)DFEAT * DFEAT * 2);      // 128 KB
  _Float16*       Y   = (_Float16*)       take((size_t)NNODES * DFEAT * 2);     // 4 MB

  gcn_all<<<NBLK, NTHR, 0, stream>>>(x, ei, W, b, E, ctl, deg, adj, Wh, Wl, Y, out);
}

// Round 9
// 108.573 us; speedup vs baseline: 2.4209x; 2.4209x over previous
//
#include <hip/hip_runtime.h>
#include <hip/hip_fp16.h>

// GCN layer, N=8192, E=262144, D=256.  3 dispatches:
//   k1 gcn_gemm  : zero bitmap (folded) + Y(fp16) = X @ (Wh+Wl)^T  (fp16 2-pass MFMA)
//   k2 gcn_scatter: pure atomicOr bitmap dedup scatter
//   k3 gcn_aggregate: wave-per-node bitmap scan -> LDS list -> 512B/row gather
// out = adj_norm @ (X @ W^T) + b  (adj_norm rows sum to 1 -> bias commutes).
// Self-edge -> diagonal 2.0 (self term + listed once); divisor = ndistinct+1.

#define NNODES 8192
#define DFEAT  256
#define WPR    256            // bitmap words per row (8192/32)
#define LISTCAP 256

typedef __attribute__((ext_vector_type(8))) _Float16 f16x8;
typedef __attribute__((ext_vector_type(4))) _Float16 f16x4;
typedef __attribute__((ext_vector_type(4))) float    f32x4;

// ---- k1: bitmap zero + W split (in-register) + Y = X @ (Wh+Wl)^T ---------
// 256 blocks x 256 thr: block = (row-tile 64) x (col-half 128).
// W is converted on the fly by every block? No: W split is tiny; convert the
// two 128-col halves of W inside each block? That re-does work 128x. Instead:
// W fp32 loaded directly and split in-register per B-fragment (cheap VALU).
__global__ __launch_bounds__(256) void gcn_gemm(
    const float* __restrict__ X, const float* __restrict__ W,
    _Float16* __restrict__ Y, uint4* __restrict__ bitmap4) {
  const int bid = blockIdx.x, tid = threadIdx.x;
  const int gtid = bid * 256 + tid;

  // fold: zero 8MB bitmap (65536 threads x 128B streaming stores)
  {
    const uint4 z = {0u, 0u, 0u, 0u};
#pragma unroll
    for (int i = 0; i < 8; ++i) bitmap4[(size_t)gtid * 8 + i] = z;
  }

  const int wave = tid >> 6, lane = tid & 63;
  const int row0 = (bid >> 1) * 64 + wave * 16;
  const int col0 = (bid & 1) * 128;
  const int lr = lane & 15;
  const int kh = (lane >> 4) * 8;

  f32x4 acc[8];
#pragma unroll
  for (int i = 0; i < 8; ++i) acc[i] = (f32x4){0.f, 0.f, 0.f, 0.f};

  const float* ap = X + (size_t)(row0 + lr) * DFEAT + kh;
  const float* wp = W + (size_t)(col0 + lr) * DFEAT + kh;

#pragma unroll
  for (int k0 = 0; k0 < DFEAT; k0 += 32) {
    float4 x0 = *(const float4*)(ap + k0);
    float4 x1 = *(const float4*)(ap + k0 + 4);
    f16x8 a = {(_Float16)x0.x, (_Float16)x0.y, (_Float16)x0.z, (_Float16)x0.w,
               (_Float16)x1.x, (_Float16)x1.y, (_Float16)x1.z, (_Float16)x1.w};
#pragma unroll
    for (int nt = 0; nt < 8; ++nt) {
      float4 w0 = *(const float4*)(wp + k0 + nt * 16 * DFEAT);
      float4 w1 = *(const float4*)(wp + k0 + nt * 16 * DFEAT + 4);
      f16x8 bh = {(_Float16)w0.x, (_Float16)w0.y, (_Float16)w0.z, (_Float16)w0.w,
                  (_Float16)w1.x, (_Float16)w1.y, (_Float16)w1.z, (_Float16)w1.w};
      f16x8 bl = {(_Float16)(w0.x - (float)bh[0]), (_Float16)(w0.y - (float)bh[1]),
                  (_Float16)(w0.z - (float)bh[2]), (_Float16)(w0.w - (float)bh[3]),
                  (_Float16)(w1.x - (float)bh[4]), (_Float16)(w1.y - (float)bh[5]),
                  (_Float16)(w1.z - (float)bh[6]), (_Float16)(w1.w - (float)bh[7])};
      acc[nt] = __builtin_amdgcn_mfma_f32_16x16x32_f16(a, bh, acc[nt], 0, 0, 0);
      acc[nt] = __builtin_amdgcn_mfma_f32_16x16x32_f16(a, bl, acc[nt], 0, 0, 0);
    }
  }

  // C/D: col = lane&15 (+nt*16), row = (lane>>4)*4 + r   [m89-verified]
  const int crow = row0 + (lane >> 4) * 4;
  const int ccol = col0 + lr;
#pragma unroll
  for (int nt = 0; nt < 8; ++nt)
#pragma unroll
    for (int r = 0; r < 4; ++r)
      Y[(size_t)(crow + r) * DFEAT + ccol + nt * 16] = (_Float16)acc[nt][r];
}

// ---- k2: edge scatter, bitmap dedup (pure atomicOr) ----------------------
__global__ __launch_bounds__(256) void gcn_scatter(
    const int* __restrict__ ei, int E, unsigned* __restrict__ bitmap) {
  int e = blockIdx.x * 256 + threadIdx.x;
  if (e < E) {
    int s = ei[e];                      // edge_index[0][e]
    int d = ei[E + e];                  // edge_index[1][e]
    atomicOr(&bitmap[(size_t)s * WPR + (d >> 5)], 1u << (d & 31));
  }
}

// ---- k3: out[i] = (sum_{j in row(i)} Y[j] + Y[i]) / (ndist+1) + b --------
// 2048 blocks x 256 thr; wave = one node (full 32 waves/CU occupancy).
// Lane covers 4 channels (8B f16x4 loads -> one 512B transaction per row).
__global__ __launch_bounds__(256) void gcn_aggregate(
    const unsigned* __restrict__ bitmap, const _Float16* __restrict__ Y,
    const float* __restrict__ bias, float* __restrict__ out) {
  __shared__ unsigned short listS[4][LISTCAP];
  __shared__ int cntS[4];

  const int tid = threadIdx.x;
  const int wave = tid >> 6, lane = tid & 63;
  const int node = blockIdx.x * 4 + wave;
  unsigned short* list = listS[wave];

  if (lane == 0) cntS[wave] = 0;
  // build neighbor list from this node's bitmap row (dedup'd, order-free)
  uint4 wv = *(const uint4*)(bitmap + (size_t)node * WPR + lane * 4);
  unsigned ws[4] = {wv.x, wv.y, wv.z, wv.w};
#pragma unroll
  for (int q = 0; q < 4; ++q) {
    unsigned w = ws[q];
    int base = (lane * 4 + q) * 32;
    while (w) {
      int bit = __ffs(w) - 1;
      w &= w - 1;
      int pos = atomicAdd(&cntS[wave], 1);
      if (pos < LISTCAP) list[pos] = (unsigned short)(base + bit);
    }
  }
  __syncthreads();

  const int n = min(cntS[wave], LISTCAP);
  const int ch4 = lane * 4;

  f16x4 sv = *(const f16x4*)(Y + (size_t)node * DFEAT + ch4);   // self (+I)
  f32x4 a0 = {(float)sv[0], (float)sv[1], (float)sv[2], (float)sv[3]};
  f32x4 a1 = {0.f, 0.f, 0.f, 0.f}, a2 = a1, a3 = a1;

  int k = 0;
  for (; k + 4 <= n; k += 4) {
    int j0 = list[k], j1 = list[k + 1], j2 = list[k + 2], j3 = list[k + 3];
    f16x4 r0 = *(const f16x4*)(Y + (size_t)j0 * DFEAT + ch4);
    f16x4 r1 = *(const f16x4*)(Y + (size_t)j1 * DFEAT + ch4);
    f16x4 r2 = *(const f16x4*)(Y + (size_t)j2 * DFEAT + ch4);
    f16x4 r3 = *(const f16x4*)(Y + (size_t)j3 * DFEAT + ch4);
#pragma unroll
    for (int c = 0; c < 4; ++c) {
      a0[c] += (float)r0[c]; a1[c] += (float)r1[c];
      a2[c] += (float)r2[c]; a3[c] += (float)r3[c];
    }
  }
  for (; k < n; ++k) {
    f16x4 r0 = *(const f16x4*)(Y + (size_t)list[k] * DFEAT + ch4);
#pragma unroll
    for (int c = 0; c < 4; ++c) a0[c] += (float)r0[c];
  }

  const float inv = 1.f / (float)(n + 1);
  const float4 b4 = *(const float4*)(bias + ch4);
  float4 o;
  o.x = (a0[0] + a1[0] + a2[0] + a3[0]) * inv + b4.x;
  o.y = (a0[1] + a1[1] + a2[1] + a3[1]) * inv + b4.y;
  o.z = (a0[2] + a1[2] + a2[2] + a3[2]) * inv + b4.z;
  o.w = (a0[3] + a1[3] + a2[3] + a3[3]) * inv + b4.w;
  *(float4*)(out + (size_t)node * DFEAT + ch4) = o;
}

extern "C" void kernel_launch(void* const* d_in, const int* in_sizes, int n_in,
                              void* d_out, int out_size, void* d_ws, size_t ws_size,
                              hipStream_t stream) {
  const float* x  = (const float*)d_in[0];
  const int*   ei = (const int*)d_in[1];
  const float* W  = (const float*)d_in[2];
  const float* b  = (const float*)d_in[3];
  float* out = (float*)d_out;
  const int E = in_sizes[1] / 2;

  // workspace layout (256B-aligned)
  char* p = (char*)d_ws;
  size_t off = 0;
  auto take = [&](size_t bytes) { char* r = p + off; off = (off + bytes + 255) & ~(size_t)255; return r; };
  unsigned* bitmap = (unsigned*) take((size_t)NNODES * WPR * 4);     // 8 MB
  _Float16* Y      = (_Float16*) take((size_t)NNODES * DFEAT * 2);   // 4 MB

  gcn_gemm<<<256, 256, 0, stream>>>(x, W, Y, (uint4*)bitmap);
  gcn_scatter<<<(E + 255) / 256, 256, 0, stream>>>(ei, E, bitmap);
  gcn_aggregate<<<NNODES / 4, 256, 0, stream>>>(bitmap, Y, b, out);
}